// Round 1
// 610.953 us; speedup vs baseline: 1.0528x; 1.0528x over previous
//
#include <hip/hip_runtime.h>
#include <hip/hip_bf16.h>

// Problem constants (DeltaNet_6614249636545)
#define BB 2
#define TT 4096
#define HH 16
#define DKk 128
#define DVv 128
#define HIDD 2048
#define CC 64
#define NN 64          // TT / CC
#define GG 8           // dv column groups in scan kernel
#define QSCALE 0.08838834764831845f  // 128^-0.5

static __device__ __forceinline__ unsigned short f2bf(float f) {
  unsigned u = __float_as_uint(f);
  u += 0x7fffu + ((u >> 16) & 1u);   // round-to-nearest-even
  return (unsigned short)(u >> 16);
}
static __device__ __forceinline__ float bf2f(unsigned short s) {
  return __uint_as_float(((unsigned)s) << 16);
}

// Barrier that drains ONLY LDS (lgkmcnt), leaving global loads in flight.
static __device__ __forceinline__ void barrier_lds_only() {
  asm volatile("s_waitcnt lgkmcnt(0)\n\ts_barrier" ::: "memory");
}

typedef short bf8 __attribute__((ext_vector_type(8)));
typedef float f4 __attribute__((ext_vector_type(4)));

// ---------------------------------------------------------------------------
// K0: transpose + bf16-cast projection weights: W[k][h] fp32 -> Wt[h][k] bf16
// ---------------------------------------------------------------------------
__global__ __launch_bounds__(256) void k0_wt(
    const float* __restrict__ Wb, const float* __restrict__ Wg,
    unsigned short* __restrict__ Wtb, unsigned short* __restrict__ Wtg) {
  int blk = blockIdx.x;
  const float* W = (blk < 8) ? Wb : Wg;
  unsigned short* Wt = (blk < 8) ? Wtb : Wtg;
  int k0 = (blk & 7) * 256;
  int tid = threadIdx.x;
  __shared__ unsigned short st[16][272];
  const float* p = W + (size_t)(k0 + tid) * HH;
#pragma unroll
  for (int h4 = 0; h4 < 4; h4++) {
    float4 x = *(const float4*)(p + h4 * 4);
    st[h4 * 4 + 0][tid] = f2bf(x.x);
    st[h4 * 4 + 1][tid] = f2bf(x.y);
    st[h4 * 4 + 2][tid] = f2bf(x.z);
    st[h4 * 4 + 3][tid] = f2bf(x.w);
  }
  __syncthreads();
  int h = tid >> 4, c = (tid & 15) << 4;
#pragma unroll
  for (int j = 0; j < 16; j++)
    Wt[(size_t)h * HIDD + k0 + c + j] = st[h][c + j];
}

// ---------------------------------------------------------------------------
// K1 (MFMA): beta = sigmoid(hab @ Wb), graw = hg @ Wg as skinny GEMM.
// ---------------------------------------------------------------------------
__global__ __launch_bounds__(256) void k1_beta_g(
    const float* __restrict__ hab, const float* __restrict__ hg,
    const unsigned short* __restrict__ Wtb, const unsigned short* __restrict__ Wtg,
    float* __restrict__ beta, float* __restrict__ graw) {
  int tile = blockIdx.x;               // 512 tiles of 16 tokens
  int tid = threadIdx.x;
  int w = tid >> 6, lane = tid & 63;
  int proj = w >> 1, ks = w & 1;
  int n16 = lane & 15, qd = lane >> 4;
  const float* hid = proj ? hg : hab;
  const unsigned short* Wt = proj ? Wtg : Wtb;
  size_t rowbase = (size_t)(tile * 16 + n16) * HIDD;
  int k0 = ks * 1024;

  f4 acc = {0.f, 0.f, 0.f, 0.f};
  for (int s = 0; s < 32; s++) {
    int kk = k0 + s * 32 + qd * 8;
    const float* hp = hid + rowbase + kk;
    float4 h0 = *(const float4*)hp;
    float4 h1 = *(const float4*)(hp + 4);
    bf8 a;
    a[0] = (short)f2bf(h0.x); a[1] = (short)f2bf(h0.y);
    a[2] = (short)f2bf(h0.z); a[3] = (short)f2bf(h0.w);
    a[4] = (short)f2bf(h1.x); a[5] = (short)f2bf(h1.y);
    a[6] = (short)f2bf(h1.z); a[7] = (short)f2bf(h1.w);
    bf8 b = *(const bf8*)&Wt[(size_t)n16 * HIDD + kk];
    acc = __builtin_amdgcn_mfma_f32_16x16x32_bf16(a, b, acc, 0, 0, 0);
  }

  __shared__ float red[2][16][17];
  if (ks == 1) {
#pragma unroll
    for (int r = 0; r < 4; r++) red[proj][qd * 4 + r][n16] = acc[r];
  }
  __syncthreads();
  if (ks == 0) {
#pragma unroll
    for (int r = 0; r < 4; r++) {
      float s = acc[r] + red[proj][qd * 4 + r][n16];
      size_t t = (size_t)(tile * 16 + qd * 4 + r) * HH + n16;
      if (proj == 0) beta[t] = 1.f / (1.f + expf(-s));
      else           graw[t] = s;
    }
  }
}

// ---------------------------------------------------------------------------
// K2: l2norm(q)*scale -> qn (bf16), l2norm(k) -> kn (bf16)
// ---------------------------------------------------------------------------
__global__ __launch_bounds__(256) void k2_l2norm(
    const float* __restrict__ q, const float* __restrict__ k,
    unsigned short* __restrict__ qn, unsigned short* __restrict__ kn) {
  int lane = threadIdx.x & 63, wave = threadIdx.x >> 6;
  for (int u = 0; u < 2; u++) {
    int vec = blockIdx.x * 8 + wave * 2 + u;
    size_t off = (size_t)vec * 64 + lane;
    float2 q2 = ((const float2*)q)[off];
    float2 k2 = ((const float2*)k)[off];
    float sq = q2.x * q2.x + q2.y * q2.y;
    float sk = k2.x * k2.x + k2.y * k2.y;
#pragma unroll
    for (int m = 32; m; m >>= 1) { sq += __shfl_xor(sq, m); sk += __shfl_xor(sk, m); }
    float rq = rsqrtf(sq + 1e-6f) * QSCALE;
    float rk = rsqrtf(sk + 1e-6f);
    unsigned pq = (unsigned)f2bf(q2.x * rq) | ((unsigned)f2bf(q2.y * rq) << 16);
    unsigned pk = (unsigned)f2bf(k2.x * rk) | ((unsigned)f2bf(k2.y * rk) << 16);
    ((unsigned*)qn)[off] = pq;
    ((unsigned*)kn)[off] = pk;
  }
}

// ---------------------------------------------------------------------------
// K3 (MFMA): per chunk:
//   attn = tril(q k^T), A = tril(k_beta k^T,-1), T = (I+A)^{-1} (nilpotent
//   doubling), then the R5 re-association products:
//     ATg = attn @ T            [64 x 64]  (o_intra = ATg @ x)
//     Ktg = k^T @ T             [128 x 64] (dS = Ktg @ x)   -- row-major in dk
//   so k4 never materializes vi and never gathers k^T.
// ---------------------------------------------------------------------------
#define SW 72          // stride (shorts) of 64x64 bf16 mats
// arena layout (shorts): sk [0,8704) stays LIVE through inversion (needed for
// Ktg gather at the end); sq [8704,17408) is dead after the attn phase and is
// overlaid by the M-buffers.
#define K3_M0R 8704
#define K3_M0T 13312
#define K3_M1R 17920
#define K3_M1T 22528
#define K3_TB  27136   // T^T (col-major shadow of T), bf16
#define K3_ARENA 31744 // 63488 B

__global__ __launch_bounds__(256) void k3_chunk(
    const unsigned short* __restrict__ qn, const unsigned short* __restrict__ kn,
    const float* __restrict__ beta,
    unsigned short* __restrict__ ATg, unsigned short* __restrict__ Ktg) {
  int cid = blockIdx.x;
  int n = cid & (NN - 1);
  int bh = cid / NN;
  int h = bh & (HH - 1);
  int b = bh / HH;
  int tid = threadIdx.x;
  int w = tid >> 6;
  int lane = tid & 63;
  int n16 = lane & 15;
  int qd = lane >> 4;
  int r0 = w * 16;

  __shared__ __align__(16) unsigned short arena[K3_ARENA];
  __shared__ float sb[CC];
  unsigned short* sk = arena;           // [c][dk] stride 136, 8704 shorts, LIVE
  unsigned short* sq = arena + 8704;    // aliased by M buffers after attn

  int t0 = n * CC;
#pragma unroll
  for (int p = 0; p < 4; p++) {
    int id = p * 256 + tid, row = id >> 4, c8 = (id & 15) << 3;
    size_t g = ((size_t)((b * TT + t0 + row) * HH + h)) * DKk + c8;
    *(uint4*)&sk[row * 136 + c8] = *(const uint4*)(kn + g);
    *(uint4*)&sq[row * 136 + c8] = *(const uint4*)(qn + g);
  }
  if (tid < CC) sb[tid] = beta[(size_t)((b * TT + t0 + tid) * HH + h)];
  __syncthreads();

  // ---- attn = q k^T and raw kk = k k^T   (MFMA, K=128)
  f4 at[4], mk[4];
#pragma unroll
  for (int ct = 0; ct < 4; ct++) { at[ct] = (f4){0,0,0,0}; mk[ct] = (f4){0,0,0,0}; }
#pragma unroll
  for (int s = 0; s < 4; s++) {
    bf8 aq = *(const bf8*)&sq[(r0 + n16) * 136 + s * 32 + qd * 8];
    bf8 ak = *(const bf8*)&sk[(r0 + n16) * 136 + s * 32 + qd * 8];
#pragma unroll
    for (int ct = 0; ct < 4; ct++) {
      bf8 bk = *(const bf8*)&sk[(ct * 16 + n16) * 136 + s * 32 + qd * 8];
      at[ct] = __builtin_amdgcn_mfma_f32_16x16x32_bf16(aq, bk, at[ct], 0, 0, 0);
      mk[ct] = __builtin_amdgcn_mfma_f32_16x16x32_bf16(ak, bk, mk[ct], 0, 0, 0);
    }
  }

  f4 tf[4];
  float mpv[4][4];
#pragma unroll
  for (int ct = 0; ct < 4; ct++) {
#pragma unroll
    for (int r = 0; r < 4; r++) {
      int i = r0 + qd * 4 + r, j = ct * 16 + n16;
      at[ct][r] = (j <= i) ? at[ct][r] : 0.f;      // masked attn, kept in regs
      float mp = (j < i) ? -sb[i] * mk[ct][r] : 0.f;
      mpv[ct][r] = mp;
      tf[ct][r] = (i == j) ? 1.f : mp;
    }
  }
  __syncthreads();   // reads of sq done; M region (overlapping sq) usable

#pragma unroll
  for (int ct = 0; ct < 4; ct++) {
#pragma unroll
    for (int r = 0; r < 4; r++) {
      int i = r0 + qd * 4 + r, j = ct * 16 + n16;
      unsigned short hm = f2bf(mpv[ct][r]);
      arena[K3_M0R + i * SW + j] = hm;
      arena[K3_M0T + j * SW + i] = hm;
      arena[K3_TB + j * SW + i] = f2bf(tf[ct][r]);
    }
  }
  __syncthreads();

  int p = 0;
  for (int it = 1; it <= 5; it++) {
    int mrp = p ? K3_M1R : K3_M0R, mtp = p ? K3_M1T : K3_M0T;
    int mrn = p ? K3_M0R : K3_M1R, mtn = p ? K3_M0T : K3_M1T;
    f4 nr[4];
#pragma unroll
    for (int ct = 0; ct < 4; ct++) nr[ct] = (f4){0,0,0,0};
#pragma unroll
    for (int s = 0; s < 2; s++) {
      bf8 a = *(const bf8*)&arena[mrp + (r0 + n16) * SW + s * 32 + qd * 8];
#pragma unroll
      for (int ct = 0; ct < 4; ct++) {
        bf8 bb = *(const bf8*)&arena[mtp + (ct * 16 + n16) * SW + s * 32 + qd * 8];
        nr[ct] = __builtin_amdgcn_mfma_f32_16x16x32_bf16(a, bb, nr[ct], 0, 0, 0);
      }
    }
#pragma unroll
    for (int ct = 0; ct < 4; ct++) {
#pragma unroll
      for (int r = 0; r < 4; r++) {
        int i = r0 + qd * 4 + r, j = ct * 16 + n16;
        unsigned short hm = f2bf(nr[ct][r]);
        arena[mrn + i * SW + j] = hm;
        arena[mtn + j * SW + i] = hm;
      }
    }
    __syncthreads();  // B1

    // phase B: Tf += N · T
#pragma unroll
    for (int s = 0; s < 2; s++) {
      bf8 a = *(const bf8*)&arena[mrn + (r0 + n16) * SW + s * 32 + qd * 8];
#pragma unroll
      for (int ct = 0; ct < 4; ct++) {
        bf8 bb = *(const bf8*)&arena[K3_TB + (ct * 16 + n16) * SW + s * 32 + qd * 8];
        tf[ct] = __builtin_amdgcn_mfma_f32_16x16x32_bf16(a, bb, tf[ct], 0, 0, 0);
      }
    }
    __syncthreads();  // B2

    if (it < 5) {
#pragma unroll
      for (int ct = 0; ct < 4; ct++) {
#pragma unroll
        for (int r = 0; r < 4; r++) {
          int i = r0 + qd * 4 + r, j = ct * 16 + n16;
          arena[K3_TB + j * SW + i] = f2bf(tf[ct][r]);
        }
      }
    }
    p = 1 - p;
  }

  // ---- post-loop: attn -> M0R (dead), FINAL T^T -> TB
#pragma unroll
  for (int ct = 0; ct < 4; ct++) {
#pragma unroll
    for (int r = 0; r < 4; r++) {
      int i = r0 + qd * 4 + r, j = ct * 16 + n16;
      arena[K3_M0R + i * SW + j] = f2bf(at[ct][r]);
      arena[K3_TB + j * SW + i] = f2bf(tf[ct][r]);
    }
  }
  __syncthreads();

  // ---- ATg = attn @ T   (A = M0R rows, B = TB rows; D[i][j])
  {
    f4 ac[4];
#pragma unroll
    for (int ct = 0; ct < 4; ct++) ac[ct] = (f4){0,0,0,0};
#pragma unroll
    for (int s = 0; s < 2; s++) {
      bf8 a = *(const bf8*)&arena[K3_M0R + (r0 + n16) * SW + s * 32 + qd * 8];
#pragma unroll
      for (int ct = 0; ct < 4; ct++) {
        bf8 bb = *(const bf8*)&arena[K3_TB + (ct * 16 + n16) * SW + s * 32 + qd * 8];
        ac[ct] = __builtin_amdgcn_mfma_f32_16x16x32_bf16(a, bb, ac[ct], 0, 0, 0);
      }
    }
    size_t abase = (size_t)cid * (CC * CC);
#pragma unroll
    for (int ct = 0; ct < 4; ct++)
#pragma unroll
      for (int r = 0; r < 4; r++)
        ATg[abase + (r0 + qd * 4 + r) * CC + ct * 16 + n16] = f2bf(ac[ct][r]);
  }

  // ---- Ktg = k^T @ T   (wave w owns dk rows w*32..w*32+31; A gathered once)
  {
    size_t kbase = (size_t)cid * (DKk * CC);
#pragma unroll
    for (int t = 0; t < 2; t++) {
      int dkt = w * 32 + t * 16;
      f4 ac[4];
#pragma unroll
      for (int ct = 0; ct < 4; ct++) ac[ct] = (f4){0,0,0,0};
#pragma unroll
      for (int s = 0; s < 2; s++) {
        bf8 a;
#pragma unroll
        for (int jj = 0; jj < 8; jj++)
          a[jj] = (short)sk[(s * 32 + qd * 8 + jj) * 136 + dkt + n16];
#pragma unroll
        for (int ct = 0; ct < 4; ct++) {
          bf8 bb = *(const bf8*)&arena[K3_TB + (ct * 16 + n16) * SW + s * 32 + qd * 8];
          ac[ct] = __builtin_amdgcn_mfma_f32_16x16x32_bf16(a, bb, ac[ct], 0, 0, 0);
        }
      }
#pragma unroll
      for (int ct = 0; ct < 4; ct++)
#pragma unroll
        for (int r = 0; r < 4; r++)
          Ktg[kbase + (dkt + qd * 4 + r) * CC + ct * 16 + n16] = f2bf(ac[ct][r]);
    }
  }
}

// ---------------------------------------------------------------------------
// K4 (MFMA): sequential chunk scan, R5 restructure. block = (b,h,jg), 16 DV
// cols, 4 waves. Per chunk only TWO barriers (the serial-dependency floor):
//   B1: staging visible (+ S^T(n-1) writes visible)
//   phase1: x = beta*(v - k@S) -> sxT[buf];  oacc = q@S   (independent)
//   B2: x visible (+ all S^T reads complete)
//   phase2: o = oacc + AT@x -> global;  S += Kt@x;  write S^T -> sSb
// sAT/sKt/sxT are double-buffered so staging(n+1) never races phase2(n);
// sk/sq/sb are read only in phase1 and fenced by B2. No k^T gather remains.
// ---------------------------------------------------------------------------
__global__ __launch_bounds__(256) void k4_scan(
    const unsigned short* __restrict__ qn, const unsigned short* __restrict__ kn,
    const float* __restrict__ v, const float* __restrict__ beta,
    const unsigned short* __restrict__ ATg, const unsigned short* __restrict__ Ktg,
    float* __restrict__ o) {
  int bi = blockIdx.x;                 // jg*32 + bh
  int jg = bi >> 5;
  int bh = bi & 31;
  int h = bh & (HH - 1);
  int b = bh >> 4;
  int tid = threadIdx.x;
  int j0 = jg * 16;
  int w = tid >> 6;
  int lane = tid & 63;
  int n16 = lane & 15;
  int qd = lane >> 4;
  int r0 = w * 16;                     // chunk-row tile of this wave
  int dkbase = w * 32;                 // S dk-rows owned by this wave

  __shared__ __align__(16) unsigned short sk[CC * 136];      // 17408 B [c][dk]
  __shared__ __align__(16) unsigned short sq[CC * 136];      // 17408 B
  __shared__ __align__(16) unsigned short sSb[16 * 136];     //  4352 B S^T: [col][dk]
  __shared__ __align__(16) unsigned short sAT[2][CC * SW];   // 2x 9216 B attn@T
  __shared__ __align__(16) unsigned short sKt[2][DKk * SW];  // 2x18432 B k^T@T [dk][c]
  __shared__ __align__(16) unsigned short sxT[2][16 * SW];   // 2x 2304 B x^T: [col][c]
  __shared__ float sb[CC];                                   //   256 B

  f4 S0 = {0.f, 0.f, 0.f, 0.f}, S1 = {0.f, 0.f, 0.f, 0.f};
  for (int i = tid; i < 16 * 136; i += 256) sSb[i] = 0;

  int bhBase = (b * HH + h) * NN;

  uint4 pk[4], pq[4], pat[2], pkt[4];
  float4 pv;
  float pb = 0.f;

  // prefetch chunk 0
  {
#pragma unroll
    for (int p = 0; p < 4; p++) {
      int id = p * 256 + tid, row = id >> 4, c8 = (id & 15) << 3;
      size_t g = ((size_t)((b * TT + row) * HH + h)) * DKk + c8;
      pk[p] = *(const uint4*)(kn + g);
      pq[p] = *(const uint4*)(qn + g);
    }
    size_t cb = (size_t)bhBase * (CC * CC);
#pragma unroll
    for (int p = 0; p < 2; p++) {
      int id = p * 256 + tid, row = id >> 3, c8 = (id & 7) << 3;
      pat[p] = *(const uint4*)(ATg + cb + row * CC + c8);
    }
    size_t kb = (size_t)bhBase * (DKk * CC);
#pragma unroll
    for (int p = 0; p < 4; p++) {
      int id = p * 256 + tid, row = id >> 3, c8 = (id & 7) << 3;
      pkt[p] = *(const uint4*)(Ktg + kb + row * CC + c8);
    }
    {
      int c = tid >> 2, c4 = (tid & 3) << 2;
      pv = *(const float4*)(v + ((size_t)((b * TT + c) * HH + h)) * DVv + j0 + c4);
    }
    if (tid < CC) pb = beta[(size_t)((b * TT + tid) * HH + h)];
  }

  for (int n = 0; n < NN; n++) {
    int t0 = n * CC;
    unsigned short* xT = sxT[n & 1];
    unsigned short* aT = sAT[n & 1];
    unsigned short* kT = sKt[n & 1];

    // ---- stage regs -> LDS
#pragma unroll
    for (int p = 0; p < 4; p++) {
      int id = p * 256 + tid, row = id >> 4, c8 = (id & 15) << 3;
      *(uint4*)&sk[row * 136 + c8] = pk[p];
      *(uint4*)&sq[row * 136 + c8] = pq[p];
    }
#pragma unroll
    for (int p = 0; p < 2; p++) {
      int id = p * 256 + tid, row = id >> 3, c8 = (id & 7) << 3;
      *(uint4*)&aT[row * SW + c8] = pat[p];
    }
#pragma unroll
    for (int p = 0; p < 4; p++) {
      int id = p * 256 + tid, row = id >> 3, c8 = (id & 7) << 3;
      *(uint4*)&kT[row * SW + c8] = pkt[p];
    }
    {
      int c = tid >> 2, c4 = (tid & 3) << 2;
      xT[(c4 + 0) * SW + c] = f2bf(pv.x);
      xT[(c4 + 1) * SW + c] = f2bf(pv.y);
      xT[(c4 + 2) * SW + c] = f2bf(pv.z);
      xT[(c4 + 3) * SW + c] = f2bf(pv.w);
    }
    if (tid < CC) sb[tid] = pb;
    barrier_lds_only();   // B1: staging + S^T(n-1) visible (LDS only)

    // ---- prefetch next chunk into regs (in flight across both phases)
    if (n + 1 < NN) {
      int t0n = t0 + CC;
#pragma unroll
      for (int p = 0; p < 4; p++) {
        int id = p * 256 + tid, row = id >> 4, c8 = (id & 15) << 3;
        size_t g = ((size_t)((b * TT + t0n + row) * HH + h)) * DKk + c8;
        pk[p] = *(const uint4*)(kn + g);
        pq[p] = *(const uint4*)(qn + g);
      }
      size_t cb = (size_t)(bhBase + n + 1) * (CC * CC);
#pragma unroll
      for (int p = 0; p < 2; p++) {
        int id = p * 256 + tid, row = id >> 3, c8 = (id & 7) << 3;
        pat[p] = *(const uint4*)(ATg + cb + row * CC + c8);
      }
      size_t kb = (size_t)(bhBase + n + 1) * (DKk * CC);
#pragma unroll
      for (int p = 0; p < 4; p++) {
        int id = p * 256 + tid, row = id >> 3, c8 = (id & 7) << 3;
        pkt[p] = *(const uint4*)(Ktg + kb + row * CC + c8);
      }
      {
        int c = tid >> 2, c4 = (tid & 3) << 2;
        pv = *(const float4*)(v + ((size_t)((b * TT + t0n + c) * HH + h)) * DVv + j0 + c4);
      }
      if (tid < CC) pb = beta[(size_t)((b * TT + t0n + tid) * HH + h)];
    }

    f4 oacc;
    // ---- phase1: x^T = beta * (v - k@S)^T (in-place in xT); oacc = q@S_old
    {
      bf8 bS0 = *(const bf8*)&sSb[n16 * 136 + 0 * 32 + qd * 8];
      bf8 bS1 = *(const bf8*)&sSb[n16 * 136 + 1 * 32 + qd * 8];
      bf8 bS2 = *(const bf8*)&sSb[n16 * 136 + 2 * 32 + qd * 8];
      bf8 bS3 = *(const bf8*)&sSb[n16 * 136 + 3 * 32 + qd * 8];
      bf8 aK0 = *(const bf8*)&sk[(r0 + n16) * 136 + 0 * 32 + qd * 8];
      bf8 aK1 = *(const bf8*)&sk[(r0 + n16) * 136 + 1 * 32 + qd * 8];
      bf8 aK2 = *(const bf8*)&sk[(r0 + n16) * 136 + 2 * 32 + qd * 8];
      bf8 aK3 = *(const bf8*)&sk[(r0 + n16) * 136 + 3 * 32 + qd * 8];
      bf8 aQ0 = *(const bf8*)&sq[(r0 + n16) * 136 + 0 * 32 + qd * 8];
      bf8 aQ1 = *(const bf8*)&sq[(r0 + n16) * 136 + 1 * 32 + qd * 8];
      bf8 aQ2 = *(const bf8*)&sq[(r0 + n16) * 136 + 2 * 32 + qd * 8];
      bf8 aQ3 = *(const bf8*)&sq[(r0 + n16) * 136 + 3 * 32 + qd * 8];
      f4 xa = {0.f, 0.f, 0.f, 0.f}, xc = {0.f, 0.f, 0.f, 0.f};
      f4 oa = {0.f, 0.f, 0.f, 0.f}, ob = {0.f, 0.f, 0.f, 0.f};
      xa = __builtin_amdgcn_mfma_f32_16x16x32_bf16(aK0, bS0, xa, 0, 0, 0);
      xa = __builtin_amdgcn_mfma_f32_16x16x32_bf16(aK1, bS1, xa, 0, 0, 0);
      xc = __builtin_amdgcn_mfma_f32_16x16x32_bf16(aK2, bS2, xc, 0, 0, 0);
      xc = __builtin_amdgcn_mfma_f32_16x16x32_bf16(aK3, bS3, xc, 0, 0, 0);
      oa = __builtin_amdgcn_mfma_f32_16x16x32_bf16(aQ0, bS0, oa, 0, 0, 0);
      oa = __builtin_amdgcn_mfma_f32_16x16x32_bf16(aQ1, bS1, oa, 0, 0, 0);
      ob = __builtin_amdgcn_mfma_f32_16x16x32_bf16(aQ2, bS2, ob, 0, 0, 0);
      ob = __builtin_amdgcn_mfma_f32_16x16x32_bf16(aQ3, bS3, ob, 0, 0, 0);
      oacc = oa + ob;
#pragma unroll
      for (int r = 0; r < 4; r++) {
        int c = r0 + qd * 4 + r;
        float vv = bf2f(xT[n16 * SW + c]);
        xT[n16 * SW + c] = f2bf(sb[c] * (vv - (xa[r] + xc[r])));
      }
    }
    barrier_lds_only();   // B2: x visible; all sSb reads complete

    // ---- phase2: o = oacc + AT@x -> global;  S += Kt@x;  S^T -> sSb
    {
      bf8 bx0 = *(const bf8*)&xT[n16 * SW + 0 * 32 + qd * 8];
      bf8 bx1 = *(const bf8*)&xT[n16 * SW + 1 * 32 + qd * 8];
      bf8 aA0 = *(const bf8*)&aT[(r0 + n16) * SW + 0 * 32 + qd * 8];
      bf8 aA1 = *(const bf8*)&aT[(r0 + n16) * SW + 1 * 32 + qd * 8];
      oacc = __builtin_amdgcn_mfma_f32_16x16x32_bf16(aA0, bx0, oacc, 0, 0, 0);
      oacc = __builtin_amdgcn_mfma_f32_16x16x32_bf16(aA1, bx1, oacc, 0, 0, 0);
#pragma unroll
      for (int r = 0; r < 4; r++) {
        int c = r0 + qd * 4 + r;
        o[((size_t)((b * TT + t0 + c) * HH + h)) * DVv + j0 + n16] = oacc[r];
      }
      bf8 aT0 = *(const bf8*)&kT[(dkbase + n16) * SW + 0 * 32 + qd * 8];
      bf8 aT1 = *(const bf8*)&kT[(dkbase + n16) * SW + 1 * 32 + qd * 8];
      S0 = __builtin_amdgcn_mfma_f32_16x16x32_bf16(aT0, bx0, S0, 0, 0, 0);
      S0 = __builtin_amdgcn_mfma_f32_16x16x32_bf16(aT1, bx1, S0, 0, 0, 0);
      bf8 aT2 = *(const bf8*)&kT[(dkbase + 16 + n16) * SW + 0 * 32 + qd * 8];
      bf8 aT3 = *(const bf8*)&kT[(dkbase + 16 + n16) * SW + 1 * 32 + qd * 8];
      S1 = __builtin_amdgcn_mfma_f32_16x16x32_bf16(aT2, bx0, S1, 0, 0, 0);
      S1 = __builtin_amdgcn_mfma_f32_16x16x32_bf16(aT3, bx1, S1, 0, 0, 0);
#pragma unroll
      for (int r = 0; r < 4; r++) {
        sSb[n16 * 136 + dkbase + qd * 4 + r] = f2bf(S0[r]);
        sSb[n16 * 136 + dkbase + 16 + qd * 4 + r] = f2bf(S1[r]);
      }
    }
  }
}

// ---------------------------------------------------------------------------
// K5: in-place on d_out: RMSNorm(o)*o_norm_w * swish(g), then per-head
//     projection out[t, h*128+d] = sum_v o~[v] * P[h,v,d].
// ---------------------------------------------------------------------------
__global__ __launch_bounds__(256) void k5_out(
    const float* __restrict__ graw, const float* __restrict__ onw,
    const float* __restrict__ opw, float* __restrict__ out) {
  int bi = blockIdx.x;                  // B*(T/32)*H = 4096
  int h = bi & (HH - 1);
  int tt = (bi >> 4) & 127;
  int b = bi >> 11;
  int t0 = tt * 32;
  int tid = threadIdx.x;

  __shared__ __align__(16) unsigned short sP[DVv * DKk];  // 32768 B (bf16)
  __shared__ __align__(16) float so[32 * 129];            // 16512 B
  __shared__ float smul[32];
  __shared__ float snw[DVv];

  const float* P = opw + (size_t)h * DVv * DKk;
  for (int r = 0; r < 16; r++) {
    int idx4 = r * 256 + tid;           // 4096 quads
    float4 pvv = *(const float4*)(P + ((size_t)idx4 << 2));
    unsigned p0 = (unsigned)f2bf(pvv.x) | ((unsigned)f2bf(pvv.y) << 16);
    unsigned p1 = (unsigned)f2bf(pvv.z) | ((unsigned)f2bf(pvv.w) << 16);
    *(uint2*)&sP[idx4 << 2] = make_uint2(p0, p1);
  }
  for (int r = 0; r < 16; r++) {
    int idx = r * 256 + tid;
    int t = idx >> 7, d = idx & 127;
    so[t * 129 + d] = out[((size_t)((b * TT + t0 + t) * HH + h)) * DVv + d];
  }
  if (tid < DVv) snw[tid] = onw[tid];
  __syncthreads();

  {
    int t = tid >> 3, l8 = tid & 7;
    float ss = 0.f;
    for (int j = 0; j < 16; j++) { float x = so[t * 129 + l8 + (j << 3)]; ss += x * x; }
    ss += __shfl_down(ss, 4, 8);
    ss += __shfl_down(ss, 2, 8);
    ss += __shfl_down(ss, 1, 8);
    if (l8 == 0) {
      float rms = rsqrtf(ss * (1.f / 128.f) + 1e-5f);
      float gv = graw[(size_t)((b * TT + t0 + t) * HH + h)];
      float sig = 1.f / (1.f + expf(-gv));
      smul[t] = rms * gv * sig;
    }
  }
  __syncthreads();
  for (int r = 0; r < 16; r++) {
    int idx = r * 256 + tid;
    int t = idx >> 7, d = idx & 127;
    so[t * 129 + d] *= smul[t] * snw[d];
  }
  __syncthreads();

  {
    int ttile = tid >> 5;               // 4 tokens each
    int dt = tid & 31;                  // 4 output dims each
    int tb = ttile << 2;
    int d0 = dt << 2;
    float acc[4][4];
#pragma unroll
    for (int a = 0; a < 4; a++)
#pragma unroll
      for (int e = 0; e < 4; e++) acc[a][e] = 0.f;
    for (int vv = 0; vv < DVv; vv++) {
      uint2 u = *(const uint2*)&sP[vv * DKk + d0];
      float p0 = __uint_as_float(u.x << 16);
      float p1 = __uint_as_float(u.x & 0xffff0000u);
      float p2 = __uint_as_float(u.y << 16);
      float p3 = __uint_as_float(u.y & 0xffff0000u);
#pragma unroll
      for (int a = 0; a < 4; a++) {
        float ov = so[(tb + a) * 129 + vv];
        acc[a][0] += ov * p0; acc[a][1] += ov * p1; acc[a][2] += ov * p2; acc[a][3] += ov * p3;
      }
    }
#pragma unroll
    for (int a = 0; a < 4; a++) {
      size_t go = ((size_t)((b * TT + t0 + tb + a) * HH + h)) * DKk + d0;
      float4 r; r.x = acc[a][0]; r.y = acc[a][1]; r.z = acc[a][2]; r.w = acc[a][3];
      *(float4*)(out + go) = r;
    }
  }
}

// ---------------------------------------------------------------------------
extern "C" void kernel_launch(void* const* d_in, const int* in_sizes, int n_in,
                              void* d_out, int out_size, void* d_ws, size_t ws_size,
                              hipStream_t stream) {
  (void)in_sizes; (void)n_in; (void)out_size; (void)ws_size;
  const float* hab = (const float*)d_in[0];
  const float* hg  = (const float*)d_in[1];
  const float* q   = (const float*)d_in[2];
  const float* k   = (const float*)d_in[3];
  const float* v   = (const float*)d_in[4];
  const float* Wb  = (const float*)d_in[5];
  const float* Wg  = (const float*)d_in[6];
  const float* onw = (const float*)d_in[7];
  const float* opw = (const float*)d_in[8];
  float* out = (float*)d_out;

  // ws layout (bytes): beta 512K | graw 512K | qn 32M | kn 32M | ATg 16M
  //                    | Ktg 32M | Wtb 64K | Wtg 64K   (total ~118.6 MB)
  char* ws = (char*)d_ws;
  float* beta          = (float*)(ws);
  float* graw          = (float*)(ws + 524288);
  unsigned short* qn   = (unsigned short*)(ws + 1048576);
  unsigned short* kn   = (unsigned short*)(ws + 34603008);
  unsigned short* ATg  = (unsigned short*)(ws + 68157440);
  unsigned short* Ktg  = (unsigned short*)(ws + 84934656);
  unsigned short* Wtb  = (unsigned short*)(ws + 118489088);
  unsigned short* Wtg  = (unsigned short*)(ws + 118554624);

  hipLaunchKernelGGL(k0_wt, dim3(16), dim3(256), 0, stream,
                     Wb, Wg, Wtb, Wtg);
  hipLaunchKernelGGL(k1_beta_g, dim3(TT * BB / 16), dim3(256), 0, stream,
                     hab, hg, Wtb, Wtg, beta, graw);
  hipLaunchKernelGGL(k2_l2norm, dim3(BB * TT * HH / 8), dim3(256), 0, stream,
                     q, k, qn, kn);
  hipLaunchKernelGGL(k3_chunk, dim3(BB * HH * NN), dim3(256), 0, stream,
                     qn, kn, beta, ATg, Ktg);
  hipLaunchKernelGGL(k4_scan, dim3(BB * HH * GG), dim3(256), 0, stream,
                     qn, kn, v, beta, ATg, Ktg, out);
  hipLaunchKernelGGL(k5_out, dim3(BB * (TT / 32) * HH), dim3(256), 0, stream,
                     graw, onw, opw, out);
}

// Round 2
// 533.643 us; speedup vs baseline: 1.2054x; 1.1449x over previous
//
#include <hip/hip_runtime.h>
#include <hip/hip_bf16.h>

// Problem constants (DeltaNet_6614249636545)
#define BB 2
#define TT 4096
#define HH 16
#define DKk 128
#define DVv 128
#define HIDD 2048
#define CC 64
#define NN 64          // TT / CC
#define GG 8           // dv column groups in scan kernel
#define QSCALE 0.08838834764831845f  // 128^-0.5

static __device__ __forceinline__ unsigned short f2bf(float f) {
  unsigned u = __float_as_uint(f);
  u += 0x7fffu + ((u >> 16) & 1u);   // round-to-nearest-even
  return (unsigned short)(u >> 16);
}
static __device__ __forceinline__ float bf2f(unsigned short s) {
  return __uint_as_float(((unsigned)s) << 16);
}

// Barrier that drains ONLY LDS (lgkmcnt), leaving global loads in flight.
static __device__ __forceinline__ void barrier_lds_only() {
  asm volatile("s_waitcnt lgkmcnt(0)\n\ts_barrier" ::: "memory");
}

typedef short bf8 __attribute__((ext_vector_type(8)));
typedef float f4 __attribute__((ext_vector_type(4)));

// ---------------------------------------------------------------------------
// K0: transpose + bf16-cast projection weights: W[k][h] fp32 -> Wt[h][k] bf16
// ---------------------------------------------------------------------------
__global__ __launch_bounds__(256) void k0_wt(
    const float* __restrict__ Wb, const float* __restrict__ Wg,
    unsigned short* __restrict__ Wtb, unsigned short* __restrict__ Wtg) {
  int blk = blockIdx.x;
  const float* W = (blk < 8) ? Wb : Wg;
  unsigned short* Wt = (blk < 8) ? Wtb : Wtg;
  int k0 = (blk & 7) * 256;
  int tid = threadIdx.x;
  __shared__ unsigned short st[16][272];
  const float* p = W + (size_t)(k0 + tid) * HH;
#pragma unroll
  for (int h4 = 0; h4 < 4; h4++) {
    float4 x = *(const float4*)(p + h4 * 4);
    st[h4 * 4 + 0][tid] = f2bf(x.x);
    st[h4 * 4 + 1][tid] = f2bf(x.y);
    st[h4 * 4 + 2][tid] = f2bf(x.z);
    st[h4 * 4 + 3][tid] = f2bf(x.w);
  }
  __syncthreads();
  int h = tid >> 4, c = (tid & 15) << 4;
#pragma unroll
  for (int j = 0; j < 16; j++)
    Wt[(size_t)h * HIDD + k0 + c + j] = st[h][c + j];
}

// ---------------------------------------------------------------------------
// K0p: per-head transpose of o_proj_w: P[h][v][d] fp32 -> Ppt[h][d][v] bf16.
// Lets k5's MFMA B-fragments load straight from global (L2-resident).
// ---------------------------------------------------------------------------
__global__ __launch_bounds__(256) void k0p_pt(
    const float* __restrict__ opw, unsigned short* __restrict__ Ppt) {
  int h = blockIdx.x;
  int tid = threadIdx.x;
  __shared__ unsigned short sp[128 * 132];
  const float* P = opw + (size_t)h * (DVv * DKk);
  for (int it = 0; it < 16; it++) {
    int idx = it * 256 + tid;            // 4096 float4 quads
    int vv = idx >> 5, d4 = (idx & 31) << 2;
    float4 x = *(const float4*)(P + vv * 128 + d4);
    sp[vv * 132 + d4 + 0] = f2bf(x.x);
    sp[vv * 132 + d4 + 1] = f2bf(x.y);
    sp[vv * 132 + d4 + 2] = f2bf(x.z);
    sp[vv * 132 + d4 + 3] = f2bf(x.w);
  }
  __syncthreads();
  unsigned short* dst = Ppt + (size_t)h * (DVv * DKk);
  for (int it = 0; it < 8; it++) {
    int idx = it * 256 + tid;            // 2048 groups of 8
    int d = idx >> 4, v8 = (idx & 15) << 3;
    unsigned short tmp[8];
#pragma unroll
    for (int j = 0; j < 8; j++) tmp[j] = sp[(v8 + j) * 132 + d];
    *(uint4*)&dst[d * 128 + v8] = *(uint4*)tmp;
  }
}

// ---------------------------------------------------------------------------
// K1 (MFMA): beta = sigmoid(hab @ Wb), graw = hg @ Wg as skinny GEMM.
// ---------------------------------------------------------------------------
__global__ __launch_bounds__(256) void k1_beta_g(
    const float* __restrict__ hab, const float* __restrict__ hg,
    const unsigned short* __restrict__ Wtb, const unsigned short* __restrict__ Wtg,
    float* __restrict__ beta, float* __restrict__ graw) {
  int tile = blockIdx.x;               // 512 tiles of 16 tokens
  int tid = threadIdx.x;
  int w = tid >> 6, lane = tid & 63;
  int proj = w >> 1, ks = w & 1;
  int n16 = lane & 15, qd = lane >> 4;
  const float* hid = proj ? hg : hab;
  const unsigned short* Wt = proj ? Wtg : Wtb;
  size_t rowbase = (size_t)(tile * 16 + n16) * HIDD;
  int k0 = ks * 1024;

  f4 acc = {0.f, 0.f, 0.f, 0.f};
  for (int s = 0; s < 32; s++) {
    int kk = k0 + s * 32 + qd * 8;
    const float* hp = hid + rowbase + kk;
    float4 h0 = *(const float4*)hp;
    float4 h1 = *(const float4*)(hp + 4);
    bf8 a;
    a[0] = (short)f2bf(h0.x); a[1] = (short)f2bf(h0.y);
    a[2] = (short)f2bf(h0.z); a[3] = (short)f2bf(h0.w);
    a[4] = (short)f2bf(h1.x); a[5] = (short)f2bf(h1.y);
    a[6] = (short)f2bf(h1.z); a[7] = (short)f2bf(h1.w);
    bf8 b = *(const bf8*)&Wt[(size_t)n16 * HIDD + kk];
    acc = __builtin_amdgcn_mfma_f32_16x16x32_bf16(a, b, acc, 0, 0, 0);
  }

  __shared__ float red[2][16][17];
  if (ks == 1) {
#pragma unroll
    for (int r = 0; r < 4; r++) red[proj][qd * 4 + r][n16] = acc[r];
  }
  __syncthreads();
  if (ks == 0) {
#pragma unroll
    for (int r = 0; r < 4; r++) {
      float s = acc[r] + red[proj][qd * 4 + r][n16];
      size_t t = (size_t)(tile * 16 + qd * 4 + r) * HH + n16;
      if (proj == 0) beta[t] = 1.f / (1.f + expf(-s));
      else           graw[t] = s;
    }
  }
}

// ---------------------------------------------------------------------------
// K2: l2norm(q)*scale -> qn (bf16), l2norm(k) -> kn (bf16)
// ---------------------------------------------------------------------------
__global__ __launch_bounds__(256) void k2_l2norm(
    const float* __restrict__ q, const float* __restrict__ k,
    unsigned short* __restrict__ qn, unsigned short* __restrict__ kn) {
  int lane = threadIdx.x & 63, wave = threadIdx.x >> 6;
  for (int u = 0; u < 2; u++) {
    int vec = blockIdx.x * 8 + wave * 2 + u;
    size_t off = (size_t)vec * 64 + lane;
    float2 q2 = ((const float2*)q)[off];
    float2 k2 = ((const float2*)k)[off];
    float sq = q2.x * q2.x + q2.y * q2.y;
    float sk = k2.x * k2.x + k2.y * k2.y;
#pragma unroll
    for (int m = 32; m; m >>= 1) { sq += __shfl_xor(sq, m); sk += __shfl_xor(sk, m); }
    float rq = rsqrtf(sq + 1e-6f) * QSCALE;
    float rk = rsqrtf(sk + 1e-6f);
    unsigned pq = (unsigned)f2bf(q2.x * rq) | ((unsigned)f2bf(q2.y * rq) << 16);
    unsigned pk = (unsigned)f2bf(k2.x * rk) | ((unsigned)f2bf(k2.y * rk) << 16);
    ((unsigned*)qn)[off] = pq;
    ((unsigned*)kn)[off] = pk;
  }
}

// ---------------------------------------------------------------------------
// K3 (MFMA): per chunk: attn = tril(q k^T), A = tril(k_beta k^T,-1),
//   T = (I+A)^{-1} via nilpotent doubling, then:
//     ATg = attn @ T   [64 x 64]
//     Ktg = k^T @ T    [128 x 64] (row-major in dk)
// ---------------------------------------------------------------------------
#define SW 72          // stride (shorts) of 64x64 bf16 mats
#define K3_M0R 8704
#define K3_M0T 13312
#define K3_M1R 17920
#define K3_M1T 22528
#define K3_TB  27136   // T^T (col-major shadow of T), bf16
#define K3_ARENA 31744 // 63488 B

__global__ __launch_bounds__(256) void k3_chunk(
    const unsigned short* __restrict__ qn, const unsigned short* __restrict__ kn,
    const float* __restrict__ beta,
    unsigned short* __restrict__ ATg, unsigned short* __restrict__ Ktg) {
  int cid = blockIdx.x;
  int n = cid & (NN - 1);
  int bh = cid / NN;
  int h = bh & (HH - 1);
  int b = bh / HH;
  int tid = threadIdx.x;
  int w = tid >> 6;
  int lane = tid & 63;
  int n16 = lane & 15;
  int qd = lane >> 4;
  int r0 = w * 16;

  __shared__ __align__(16) unsigned short arena[K3_ARENA];
  __shared__ float sb[CC];
  unsigned short* sk = arena;           // [c][dk] stride 136, LIVE throughout
  unsigned short* sq = arena + 8704;    // aliased by M buffers after attn

  int t0 = n * CC;
#pragma unroll
  for (int p = 0; p < 4; p++) {
    int id = p * 256 + tid, row = id >> 4, c8 = (id & 15) << 3;
    size_t g = ((size_t)((b * TT + t0 + row) * HH + h)) * DKk + c8;
    *(uint4*)&sk[row * 136 + c8] = *(const uint4*)(kn + g);
    *(uint4*)&sq[row * 136 + c8] = *(const uint4*)(qn + g);
  }
  if (tid < CC) sb[tid] = beta[(size_t)((b * TT + t0 + tid) * HH + h)];
  __syncthreads();

  // ---- attn = q k^T and raw kk = k k^T   (MFMA, K=128)
  f4 at[4], mk[4];
#pragma unroll
  for (int ct = 0; ct < 4; ct++) { at[ct] = (f4){0,0,0,0}; mk[ct] = (f4){0,0,0,0}; }
#pragma unroll
  for (int s = 0; s < 4; s++) {
    bf8 aq = *(const bf8*)&sq[(r0 + n16) * 136 + s * 32 + qd * 8];
    bf8 ak = *(const bf8*)&sk[(r0 + n16) * 136 + s * 32 + qd * 8];
#pragma unroll
    for (int ct = 0; ct < 4; ct++) {
      bf8 bk = *(const bf8*)&sk[(ct * 16 + n16) * 136 + s * 32 + qd * 8];
      at[ct] = __builtin_amdgcn_mfma_f32_16x16x32_bf16(aq, bk, at[ct], 0, 0, 0);
      mk[ct] = __builtin_amdgcn_mfma_f32_16x16x32_bf16(ak, bk, mk[ct], 0, 0, 0);
    }
  }

  f4 tf[4];
  float mpv[4][4];
#pragma unroll
  for (int ct = 0; ct < 4; ct++) {
#pragma unroll
    for (int r = 0; r < 4; r++) {
      int i = r0 + qd * 4 + r, j = ct * 16 + n16;
      at[ct][r] = (j <= i) ? at[ct][r] : 0.f;      // masked attn kept in regs
      float mp = (j < i) ? -sb[i] * mk[ct][r] : 0.f;
      mpv[ct][r] = mp;
      tf[ct][r] = (i == j) ? 1.f : mp;
    }
  }
  __syncthreads();   // reads of sq done; M region usable

#pragma unroll
  for (int ct = 0; ct < 4; ct++) {
#pragma unroll
    for (int r = 0; r < 4; r++) {
      int i = r0 + qd * 4 + r, j = ct * 16 + n16;
      unsigned short hm = f2bf(mpv[ct][r]);
      arena[K3_M0R + i * SW + j] = hm;
      arena[K3_M0T + j * SW + i] = hm;
      arena[K3_TB + j * SW + i] = f2bf(tf[ct][r]);
    }
  }
  __syncthreads();

  int p = 0;
  for (int it = 1; it <= 5; it++) {
    int mrp = p ? K3_M1R : K3_M0R, mtp = p ? K3_M1T : K3_M0T;
    int mrn = p ? K3_M0R : K3_M1R, mtn = p ? K3_M0T : K3_M1T;
    f4 nr[4];
#pragma unroll
    for (int ct = 0; ct < 4; ct++) nr[ct] = (f4){0,0,0,0};
#pragma unroll
    for (int s = 0; s < 2; s++) {
      bf8 a = *(const bf8*)&arena[mrp + (r0 + n16) * SW + s * 32 + qd * 8];
#pragma unroll
      for (int ct = 0; ct < 4; ct++) {
        bf8 bb = *(const bf8*)&arena[mtp + (ct * 16 + n16) * SW + s * 32 + qd * 8];
        nr[ct] = __builtin_amdgcn_mfma_f32_16x16x32_bf16(a, bb, nr[ct], 0, 0, 0);
      }
    }
#pragma unroll
    for (int ct = 0; ct < 4; ct++) {
#pragma unroll
      for (int r = 0; r < 4; r++) {
        int i = r0 + qd * 4 + r, j = ct * 16 + n16;
        unsigned short hm = f2bf(nr[ct][r]);
        arena[mrn + i * SW + j] = hm;
        arena[mtn + j * SW + i] = hm;
      }
    }
    __syncthreads();  // B1

    // phase B: Tf += N · T
#pragma unroll
    for (int s = 0; s < 2; s++) {
      bf8 a = *(const bf8*)&arena[mrn + (r0 + n16) * SW + s * 32 + qd * 8];
#pragma unroll
      for (int ct = 0; ct < 4; ct++) {
        bf8 bb = *(const bf8*)&arena[K3_TB + (ct * 16 + n16) * SW + s * 32 + qd * 8];
        tf[ct] = __builtin_amdgcn_mfma_f32_16x16x32_bf16(a, bb, tf[ct], 0, 0, 0);
      }
    }
    __syncthreads();  // B2

    if (it < 5) {
#pragma unroll
      for (int ct = 0; ct < 4; ct++) {
#pragma unroll
        for (int r = 0; r < 4; r++) {
          int i = r0 + qd * 4 + r, j = ct * 16 + n16;
          arena[K3_TB + j * SW + i] = f2bf(tf[ct][r]);
        }
      }
    }
    p = 1 - p;
  }

  // ---- post-loop: attn -> M0R (dead), FINAL T^T -> TB
#pragma unroll
  for (int ct = 0; ct < 4; ct++) {
#pragma unroll
    for (int r = 0; r < 4; r++) {
      int i = r0 + qd * 4 + r, j = ct * 16 + n16;
      arena[K3_M0R + i * SW + j] = f2bf(at[ct][r]);
      arena[K3_TB + j * SW + i] = f2bf(tf[ct][r]);
    }
  }
  __syncthreads();

  // ---- ATg = attn @ T
  {
    f4 ac[4];
#pragma unroll
    for (int ct = 0; ct < 4; ct++) ac[ct] = (f4){0,0,0,0};
#pragma unroll
    for (int s = 0; s < 2; s++) {
      bf8 a = *(const bf8*)&arena[K3_M0R + (r0 + n16) * SW + s * 32 + qd * 8];
#pragma unroll
      for (int ct = 0; ct < 4; ct++) {
        bf8 bb = *(const bf8*)&arena[K3_TB + (ct * 16 + n16) * SW + s * 32 + qd * 8];
        ac[ct] = __builtin_amdgcn_mfma_f32_16x16x32_bf16(a, bb, ac[ct], 0, 0, 0);
      }
    }
    size_t abase = (size_t)cid * (CC * CC);
#pragma unroll
    for (int ct = 0; ct < 4; ct++)
#pragma unroll
      for (int r = 0; r < 4; r++)
        ATg[abase + (r0 + qd * 4 + r) * CC + ct * 16 + n16] = f2bf(ac[ct][r]);
  }

  // ---- Ktg = k^T @ T   (wave w owns dk rows w*32..w*32+31)
  {
    size_t kbase = (size_t)cid * (DKk * CC);
#pragma unroll
    for (int t = 0; t < 2; t++) {
      int dkt = w * 32 + t * 16;
      f4 ac[4];
#pragma unroll
      for (int ct = 0; ct < 4; ct++) ac[ct] = (f4){0,0,0,0};
#pragma unroll
      for (int s = 0; s < 2; s++) {
        bf8 a;
#pragma unroll
        for (int jj = 0; jj < 8; jj++)
          a[jj] = (short)sk[(s * 32 + qd * 8 + jj) * 136 + dkt + n16];
#pragma unroll
        for (int ct = 0; ct < 4; ct++) {
          bf8 bb = *(const bf8*)&arena[K3_TB + (ct * 16 + n16) * SW + s * 32 + qd * 8];
          ac[ct] = __builtin_amdgcn_mfma_f32_16x16x32_bf16(a, bb, ac[ct], 0, 0, 0);
        }
      }
#pragma unroll
      for (int ct = 0; ct < 4; ct++)
#pragma unroll
        for (int r = 0; r < 4; r++)
          Ktg[kbase + (dkt + qd * 4 + r) * CC + ct * 16 + n16] = f2bf(ac[ct][r]);
    }
  }
}

// ---------------------------------------------------------------------------
// K4 (MFMA): sequential chunk scan, R6: near-LDS-free. All MFMA A-operands
// (k, q, AT, Kt fragments) are per-lane 16B slices -> loaded DIRECTLY
// global->register one chunk ahead. LDS keeps only S^T (cross-wave handoff)
// and x^T (the one true transpose). beta loaded per-lane from global.
// v staged per-wave into xT (wave-local handoff: no barrier needed).
// Two barriers per chunk = the serial-dependency floor.
// ---------------------------------------------------------------------------
struct K4Frag {
  bf8 k0, k1, k2, k3;      // kn rows r0+n16, k-slices
  bf8 q0, q1, q2, q3;      // qn rows r0+n16
  bf8 a0, a1;              // ATg rows r0+n16
  bf8 t0, t1, t2, t3;      // Ktg rows dkbase+n16 / dkbase+16+n16
  float4 vv;               // v[t0+r0+n16][j0+qd*4..+4]
  float b0, b1, b2, b3;    // beta rows r0+qd*4+r
};

static __device__ __forceinline__ void k4_prefetch(
    K4Frag& F, int n,
    const unsigned short* knb, const unsigned short* qnb,
    const unsigned short* atb, const unsigned short* ktb,
    const float* vb, const float* bb) {
  const unsigned short* kp = knb + (size_t)n * (CC * HH * DKk);
  F.k0 = *(const bf8*)(kp);
  F.k1 = *(const bf8*)(kp + 32);
  F.k2 = *(const bf8*)(kp + 64);
  F.k3 = *(const bf8*)(kp + 96);
  const unsigned short* qp = qnb + (size_t)n * (CC * HH * DKk);
  F.q0 = *(const bf8*)(qp);
  F.q1 = *(const bf8*)(qp + 32);
  F.q2 = *(const bf8*)(qp + 64);
  F.q3 = *(const bf8*)(qp + 96);
  const unsigned short* ap = atb + (size_t)n * (CC * CC);
  F.a0 = *(const bf8*)(ap);
  F.a1 = *(const bf8*)(ap + 32);
  const unsigned short* tp = ktb + (size_t)n * (DKk * CC);
  F.t0 = *(const bf8*)(tp);
  F.t1 = *(const bf8*)(tp + 32);
  F.t2 = *(const bf8*)(tp + 1024);
  F.t3 = *(const bf8*)(tp + 1024 + 32);
  F.vv = *(const float4*)(vb + (size_t)n * (CC * HH * DVv));
  const float* bp = bb + (size_t)n * (CC * HH);
  F.b0 = bp[0]; F.b1 = bp[HH]; F.b2 = bp[2 * HH]; F.b3 = bp[3 * HH];
}

static __device__ __forceinline__ void k4_body(
    const K4Frag& F, K4Frag& FN, int n, bool pf,
    f4& S0, f4& S1,
    unsigned short* xT, unsigned short* sSb,
    float* opn,
    int n16, int qd, int r0, int dkbase,
    const unsigned short* knb, const unsigned short* qnb,
    const unsigned short* atb, const unsigned short* ktb,
    const float* vb, const float* bb) {
  // ---- prefetch chunk n+1 (in flight across both barriers; lgkm-only waits)
  if (pf) k4_prefetch(FN, n + 1, knb, qnb, atb, ktb, vb, bb);

  // ---- stage v (wave-local: this wave's 16 cols r0..r0+15)
  {
    int col = r0 + n16;
    xT[(qd * 4 + 0) * SW + col] = f2bf(F.vv.x);
    xT[(qd * 4 + 1) * SW + col] = f2bf(F.vv.y);
    xT[(qd * 4 + 2) * SW + col] = f2bf(F.vv.z);
    xT[(qd * 4 + 3) * SW + col] = f2bf(F.vv.w);
  }
  barrier_lds_only();   // B1: S^T(n-1) visible to all waves

  f4 oacc;
  // ---- phase1: x = beta*(v - k@S) (in xT, wave-local); oacc = q@S_old
  {
    bf8 bS0 = *(const bf8*)&sSb[n16 * 136 + 0 + qd * 8];
    bf8 bS1 = *(const bf8*)&sSb[n16 * 136 + 32 + qd * 8];
    bf8 bS2 = *(const bf8*)&sSb[n16 * 136 + 64 + qd * 8];
    bf8 bS3 = *(const bf8*)&sSb[n16 * 136 + 96 + qd * 8];
    f4 xa = {0.f, 0.f, 0.f, 0.f}, xc = {0.f, 0.f, 0.f, 0.f};
    f4 oa = {0.f, 0.f, 0.f, 0.f}, ob = {0.f, 0.f, 0.f, 0.f};
    xa = __builtin_amdgcn_mfma_f32_16x16x32_bf16(F.k0, bS0, xa, 0, 0, 0);
    xa = __builtin_amdgcn_mfma_f32_16x16x32_bf16(F.k1, bS1, xa, 0, 0, 0);
    xc = __builtin_amdgcn_mfma_f32_16x16x32_bf16(F.k2, bS2, xc, 0, 0, 0);
    xc = __builtin_amdgcn_mfma_f32_16x16x32_bf16(F.k3, bS3, xc, 0, 0, 0);
    oa = __builtin_amdgcn_mfma_f32_16x16x32_bf16(F.q0, bS0, oa, 0, 0, 0);
    oa = __builtin_amdgcn_mfma_f32_16x16x32_bf16(F.q1, bS1, oa, 0, 0, 0);
    ob = __builtin_amdgcn_mfma_f32_16x16x32_bf16(F.q2, bS2, ob, 0, 0, 0);
    ob = __builtin_amdgcn_mfma_f32_16x16x32_bf16(F.q3, bS3, ob, 0, 0, 0);
    oacc = oa + ob;
    float bv[4] = {F.b0, F.b1, F.b2, F.b3};
#pragma unroll
    for (int r = 0; r < 4; r++) {
      int c = r0 + qd * 4 + r;
      float vval = bf2f(xT[n16 * SW + c]);
      xT[n16 * SW + c] = f2bf(bv[r] * (vval - (xa[r] + xc[r])));
    }
  }
  barrier_lds_only();   // B2: x visible to all waves

  // ---- phase2: o = oacc + AT@x -> global;  S += Kt@x;  S^T -> sSb
  {
    bf8 bx0 = *(const bf8*)&xT[n16 * SW + qd * 8];
    bf8 bx1 = *(const bf8*)&xT[n16 * SW + 32 + qd * 8];
    oacc = __builtin_amdgcn_mfma_f32_16x16x32_bf16(F.a0, bx0, oacc, 0, 0, 0);
    oacc = __builtin_amdgcn_mfma_f32_16x16x32_bf16(F.a1, bx1, oacc, 0, 0, 0);
#pragma unroll
    for (int r = 0; r < 4; r++) opn[r * (HH * DVv)] = oacc[r];
    S0 = __builtin_amdgcn_mfma_f32_16x16x32_bf16(F.t0, bx0, S0, 0, 0, 0);
    S0 = __builtin_amdgcn_mfma_f32_16x16x32_bf16(F.t1, bx1, S0, 0, 0, 0);
    S1 = __builtin_amdgcn_mfma_f32_16x16x32_bf16(F.t2, bx0, S1, 0, 0, 0);
    S1 = __builtin_amdgcn_mfma_f32_16x16x32_bf16(F.t3, bx1, S1, 0, 0, 0);
    uint2 w0, w1;
    w0.x = (unsigned)f2bf(S0[0]) | ((unsigned)f2bf(S0[1]) << 16);
    w0.y = (unsigned)f2bf(S0[2]) | ((unsigned)f2bf(S0[3]) << 16);
    w1.x = (unsigned)f2bf(S1[0]) | ((unsigned)f2bf(S1[1]) << 16);
    w1.y = (unsigned)f2bf(S1[2]) | ((unsigned)f2bf(S1[3]) << 16);
    *(uint2*)&sSb[n16 * 136 + dkbase + qd * 4] = w0;
    *(uint2*)&sSb[n16 * 136 + dkbase + 16 + qd * 4] = w1;
  }
}

__global__ __launch_bounds__(256, 1) void k4_scan(
    const unsigned short* __restrict__ qn, const unsigned short* __restrict__ kn,
    const float* __restrict__ v, const float* __restrict__ beta,
    const unsigned short* __restrict__ ATg, const unsigned short* __restrict__ Ktg,
    float* __restrict__ o) {
  int bi = blockIdx.x;                 // jg*32 + bh  (same-bh blocks share XCD)
  int jg = bi >> 5;
  int bh = bi & 31;
  int h = bh & (HH - 1);
  int b = bh >> 4;
  int tid = threadIdx.x;
  int j0 = jg * 16;
  int w = tid >> 6;
  int lane = tid & 63;
  int n16 = lane & 15;
  int qd = lane >> 4;
  int r0 = w * 16;                     // chunk-row tile of this wave
  int dkbase = w * 32;                 // S dk-rows owned by this wave

  __shared__ __align__(16) unsigned short sSb[16 * 136];     // 4352 B S^T [col][dk]
  __shared__ __align__(16) unsigned short sxT[2][16 * SW];   // 2x2304 B x^T [col][c]

  f4 S0 = {0.f, 0.f, 0.f, 0.f}, S1 = {0.f, 0.f, 0.f, 0.f};
  for (int i = tid; i < 16 * 136; i += 256) sSb[i] = 0;

  // lane-adjusted base pointers (chunk 0)
  const unsigned short* knb =
      kn + ((size_t)((b * TT + r0 + n16) * HH + h)) * DKk + qd * 8;
  const unsigned short* qnb =
      qn + ((size_t)((b * TT + r0 + n16) * HH + h)) * DKk + qd * 8;
  size_t bhN = (size_t)(b * HH + h) * NN;
  const unsigned short* atb = ATg + bhN * (CC * CC) + (r0 + n16) * 64 + qd * 8;
  const unsigned short* ktb = Ktg + bhN * (DKk * CC) + (dkbase + n16) * 64 + qd * 8;
  const float* vb =
      v + ((size_t)((b * TT + r0 + n16) * HH + h)) * DVv + j0 + qd * 4;
  const float* bb = beta + (size_t)((b * TT + r0 + qd * 4) * HH + h);
  float* opb =
      o + ((size_t)((b * TT + r0 + qd * 4) * HH + h)) * DVv + j0 + n16;

  K4Frag FA, FB;
  k4_prefetch(FA, 0, knb, qnb, atb, ktb, vb, bb);

  for (int n = 0; n < NN; n += 2) {
    k4_body(FA, FB, n, true, S0, S1, sxT[0], sSb,
            opb + (size_t)n * (CC * HH * DVv),
            n16, qd, r0, dkbase, knb, qnb, atb, ktb, vb, bb);
    k4_body(FB, FA, n + 1, n + 2 < NN, S0, S1, sxT[1], sSb,
            opb + (size_t)(n + 1) * (CC * HH * DVv),
            n16, qd, r0, dkbase, knb, qnb, atb, ktb, vb, bb);
  }
}

// ---------------------------------------------------------------------------
// K5: in-place on d_out: RMSNorm(o)*o_norm_w * swish(g), then per-head
//     projection via MFMA with pre-transposed Ppt[h][d][v] bf16.
// ---------------------------------------------------------------------------
__global__ __launch_bounds__(256) void k5_out(
    const float* __restrict__ graw, const float* __restrict__ onw,
    const unsigned short* __restrict__ Ppt, float* __restrict__ out) {
  int bi = blockIdx.x;                  // B*(T/32)*H = 4096
  int h = bi & (HH - 1);
  int tt = (bi >> 4) & 127;
  int b = bi >> 11;
  int t0 = tt * 32;
  int tid = threadIdx.x;
  int w = tid >> 6;
  int lane = tid & 63;
  int n16 = lane & 15;
  int qd = lane >> 4;

  __shared__ __align__(16) float so[32 * 132];            // 16896 B
  __shared__ float smul[32];
  __shared__ float snw[DVv];

  for (int r = 0; r < 16; r++) {
    int idx = r * 256 + tid;
    int t = idx >> 7, d = idx & 127;
    so[t * 132 + d] = out[((size_t)((b * TT + t0 + t) * HH + h)) * DVv + d];
  }
  if (tid < DVv) snw[tid] = onw[tid];
  __syncthreads();

  {
    int t = tid >> 3, l8 = tid & 7;
    float ss = 0.f;
    for (int j = 0; j < 16; j++) { float x = so[t * 132 + l8 + (j << 3)]; ss += x * x; }
    ss += __shfl_down(ss, 4, 8);
    ss += __shfl_down(ss, 2, 8);
    ss += __shfl_down(ss, 1, 8);
    if (l8 == 0) {
      float rms = rsqrtf(ss * (1.f / 128.f) + 1e-5f);
      float gv = graw[(size_t)((b * TT + t0 + t) * HH + h)];
      float sig = 1.f / (1.f + expf(-gv));
      smul[t] = rms * gv * sig;
    }
  }
  __syncthreads();
  for (int r = 0; r < 16; r++) {
    int idx = r * 256 + tid;
    int t = idx >> 7, d = idx & 127;
    so[t * 132 + d] *= smul[t] * snw[d];
  }
  __syncthreads();

  // ---- projection: out[t][d] = sum_v o~[t][v] * P[v][d]  (MFMA)
  {
    const unsigned short* Pb = Ppt + (size_t)h * (DVv * DKk);
    int dt0 = w * 2;                    // wave's two 16-col d-tiles
#pragma unroll
    for (int m = 0; m < 2; m++) {
      bf8 A[4];
#pragma unroll
      for (int ks = 0; ks < 4; ks++) {
        const float* sp = &so[(m * 16 + n16) * 132 + ks * 32 + qd * 8];
        float4 f0 = *(const float4*)sp;
        float4 f1 = *(const float4*)(sp + 4);
        A[ks][0] = (short)f2bf(f0.x); A[ks][1] = (short)f2bf(f0.y);
        A[ks][2] = (short)f2bf(f0.z); A[ks][3] = (short)f2bf(f0.w);
        A[ks][4] = (short)f2bf(f1.x); A[ks][5] = (short)f2bf(f1.y);
        A[ks][6] = (short)f2bf(f1.z); A[ks][7] = (short)f2bf(f1.w);
      }
#pragma unroll
      for (int dti = 0; dti < 2; dti++) {
        int dt = dt0 + dti;
        f4 acc = {0.f, 0.f, 0.f, 0.f};
#pragma unroll
        for (int ks = 0; ks < 4; ks++) {
          bf8 Bf = *(const bf8*)(Pb + (dt * 16 + n16) * 128 + ks * 32 + qd * 8);
          acc = __builtin_amdgcn_mfma_f32_16x16x32_bf16(A[ks], Bf, acc, 0, 0, 0);
        }
#pragma unroll
        for (int r = 0; r < 4; r++) {
          size_t go = ((size_t)(b * TT + t0 + m * 16 + qd * 4 + r)) * (HH * DKk)
                      + h * DKk + dt * 16 + n16;
          out[go] = acc[r];
        }
      }
    }
  }
}

// ---------------------------------------------------------------------------
extern "C" void kernel_launch(void* const* d_in, const int* in_sizes, int n_in,
                              void* d_out, int out_size, void* d_ws, size_t ws_size,
                              hipStream_t stream) {
  (void)in_sizes; (void)n_in; (void)out_size; (void)ws_size;
  const float* hab = (const float*)d_in[0];
  const float* hg  = (const float*)d_in[1];
  const float* q   = (const float*)d_in[2];
  const float* k   = (const float*)d_in[3];
  const float* v   = (const float*)d_in[4];
  const float* Wb  = (const float*)d_in[5];
  const float* Wg  = (const float*)d_in[6];
  const float* onw = (const float*)d_in[7];
  const float* opw = (const float*)d_in[8];
  float* out = (float*)d_out;

  // ws layout (bytes): beta 512K | graw 512K | qn 32M | kn 32M | ATg 16M
  //                    | Ktg 32M | Wtb 64K | Wtg 64K | Ppt 512K
  char* ws = (char*)d_ws;
  float* beta          = (float*)(ws);
  float* graw          = (float*)(ws + 524288);
  unsigned short* qn   = (unsigned short*)(ws + 1048576);
  unsigned short* kn   = (unsigned short*)(ws + 34603008);
  unsigned short* ATg  = (unsigned short*)(ws + 68157440);
  unsigned short* Ktg  = (unsigned short*)(ws + 84934656);
  unsigned short* Wtb  = (unsigned short*)(ws + 118489088);
  unsigned short* Wtg  = (unsigned short*)(ws + 118554624);
  unsigned short* Ppt  = (unsigned short*)(ws + 118620160);

  hipLaunchKernelGGL(k0_wt, dim3(16), dim3(256), 0, stream,
                     Wb, Wg, Wtb, Wtg);
  hipLaunchKernelGGL(k0p_pt, dim3(HH), dim3(256), 0, stream,
                     opw, Ppt);
  hipLaunchKernelGGL(k1_beta_g, dim3(TT * BB / 16), dim3(256), 0, stream,
                     hab, hg, Wtb, Wtg, beta, graw);
  hipLaunchKernelGGL(k2_l2norm, dim3(BB * TT * HH / 8), dim3(256), 0, stream,
                     q, k, qn, kn);
  hipLaunchKernelGGL(k3_chunk, dim3(BB * HH * NN), dim3(256), 0, stream,
                     qn, kn, beta, ATg, Ktg);
  hipLaunchKernelGGL(k4_scan, dim3(BB * HH * GG), dim3(256), 0, stream,
                     qn, kn, v, beta, ATg, Ktg, out);
  hipLaunchKernelGGL(k5_out, dim3(BB * (TT / 32) * HH), dim3(256), 0, stream,
                     graw, onw, Ppt, out);
}